// Round 13
// baseline (163.514 us; speedup 1.0000x reference)
//
#include <hip/hip_runtime.h>
#include <math.h>

#define BB 8
#define CC 128
#define NN 4096   // W*H

typedef _Float16 f16;
typedef _Float16 f16x4v __attribute__((ext_vector_type(4)));
typedef _Float16 f16x8 __attribute__((ext_vector_type(8)));
typedef float f32x4v __attribute__((ext_vector_type(4)));
typedef float f32x16 __attribute__((ext_vector_type(16)));

#if __has_builtin(__builtin_amdgcn_exp2f)
#define EXP2(x) __builtin_amdgcn_exp2f(x)
#else
#define EXP2(x) __expf((x)*0.69314718056f)
#endif

// Q rows pre-scaled by 0.25*log2(e): softmax exp is one native v_exp_f32;
// the -SHIFT bias rides in the MFMA C operand.
#define QSCALE 0.360673760222f   // 0.25 * log2(e)
#define SHIFT  5.770780163555f   // 4.0 * log2(e)

// Wf scratch lives in the tail of d_out (attn rewrites d_out afterwards).
#define WF_BYTES 65536

// ---------------------------------------------------------------------------
// prep: stack Wq*QSCALE (rows 0-15), Wk (16-31), Wv (32-159) as f16 in
// 32x32x16 A-fragment order. biasS f32[160] likewise stacked.
// ---------------------------------------------------------------------------
__global__ __launch_bounds__(256)
void prep_kernel(const float* __restrict__ Wq, const float* __restrict__ bq,
                 const float* __restrict__ Wk, const float* __restrict__ bk,
                 const float* __restrict__ Wv, const float* __restrict__ bv,
                 f16* __restrict__ Wf, float* __restrict__ biasS)
{
    const int tg = blockIdx.x*256 + threadIdx.x;   // 0..2559
    if (tg < 2560) {
        const int mt = tg >> 9, ks = (tg >> 6) & 7, l = tg & 63;
        const int n32 = l & 31, h = l >> 5;
        const int r = mt*32 + n32;
        f16x8 v8;
        #pragma unroll
        for (int i = 0; i < 8; i++) {
            int c = ks*16 + 8*h + i;
            float wv_;
            if (r < 16)      wv_ = QSCALE * Wq[r*CC + c];
            else if (r < 32) wv_ = Wk[(r-16)*CC + c];
            else             wv_ = Wv[(r-32)*CC + c];
            v8[i] = (f16)wv_;
        }
        *(f16x8*)&Wf[(size_t)tg*8] = v8;
    }
    if (blockIdx.x == 0 && threadIdx.x < 160) {
        int r = threadIdx.x;
        biasS[r] = r < 16 ? QSCALE*bq[r] : (r < 32 ? bk[r-16] : bv[r-32]);
    }
}

// ---------------------------------------------------------------------------
// Projection (r10-era version): grid 256 (b = bx&7, pt = bx>>3), block
// 256 = 4 waves, wave = 32-pixel n-tile, K=128 (8 ksteps), 40 MFMAs/wave.
// Epilogue: Qt/Kt pixel-major; V via LDS -> sigma-ordered Vf:
//   Vf[b][kt64][frag=kc*4+ct][l][i] =
//     V[c=ct*32+(l&31)][key=kt64*64 + kc*16 + (i&3)+8*(i>>2)+4*(l>>5)]
// ---------------------------------------------------------------------------
__global__ __launch_bounds__(256)
void proj_kernel(const float* __restrict__ x, const f16* __restrict__ Wf,
                 const float* __restrict__ biasS,
                 f16* __restrict__ Qt, f16* __restrict__ Kt, f16* __restrict__ Vf)
{
    __shared__ __align__(16) f16 Vl[CC*140];   // 35 KB, stride 140 halfs

    const int tid  = threadIdx.x;
    const int lane = tid & 63;
    const int wv   = tid >> 6;
    const int b    = blockIdx.x & 7;
    const int pt   = blockIdx.x >> 3;      // 0..31
    const int n32  = lane & 31;
    const int half = lane >> 5;
    const int p    = pt*128 + wv*32 + n32;

    const float* xp = x + (size_t)b*CC*NN + p;
    f16x8 xf[8];
    #pragma unroll
    for (int ks = 0; ks < 8; ks++) {
        float xv[8];
        #pragma unroll
        for (int i = 0; i < 8; i++)
            xv[i] = __builtin_nontemporal_load(&xp[(size_t)(ks*16 + 8*half + i)*NN]);
        #pragma unroll
        for (int i = 0; i < 8; i++) xf[ks][i] = (f16)xv[i];
    }

    f32x16 acc[5];
    #pragma unroll
    for (int mt = 0; mt < 5; mt++) acc[mt] = (f32x16)0.0f;
    #pragma unroll
    for (int ks = 0; ks < 8; ks++) {
        #pragma unroll
        for (int mt = 0; mt < 5; mt++) {
            f16x8 wfr = *(const f16x8*)&Wf[((size_t)(mt*8 + ks)*64 + lane)*8];
            acc[mt] = __builtin_amdgcn_mfma_f32_32x32x16_f16(wfr, xf[ks], acc[mt], 0, 0, 0);
        }
    }

    #pragma unroll
    for (int mt = 0; mt < 5; mt++) {
        #pragma unroll
        for (int q = 0; q < 4; q++) {
            float4 b4 = *(const float4*)&biasS[mt*32 + q*8 + 4*half];
            acc[mt][q*4+0] += b4.x; acc[mt][q*4+1] += b4.y;
            acc[mt][q*4+2] += b4.z; acc[mt][q*4+3] += b4.w;
        }
    }

    // mt0: rows 0-15 = Q, 16-31 = K
    {
        size_t qkoff = ((size_t)b*NN + p)*16;
        f16x4v s0, s1, s2, s3;
        #pragma unroll
        for (int i = 0; i < 4; i++) {
            s0[i] = (f16)acc[0][i];    s1[i] = (f16)acc[0][4+i];
            s2[i] = (f16)acc[0][8+i];  s3[i] = (f16)acc[0][12+i];
        }
        *(f16x4v*)&Qt[qkoff + 4*half]     = s0;
        *(f16x4v*)&Qt[qkoff + 8 + 4*half] = s1;
        *(f16x4v*)&Kt[qkoff + 4*half]     = s2;
        *(f16x4v*)&Kt[qkoff + 8 + 4*half] = s3;
    }

    // mt1-4: V channels -> LDS [c][local pixel]
    #pragma unroll
    for (int mt = 1; mt < 5; mt++) {
        #pragma unroll
        for (int g = 0; g < 16; g++) {
            int c = (mt-1)*32 + (g & 3) + 8*(g >> 2) + 4*half;
            Vl[c*140 + wv*32 + n32] = (f16)acc[mt][g];
        }
    }
    __syncthreads();

    // sigma-ordered Vf writeout
    #pragma unroll
    for (int pass = 0; pass < 8; pass++) {
        int item = pass*256 + tid;
        int l    = item & 63;
        int f    = (item >> 6) & 15;       // kc*4 + ct
        int ktl  = item >> 10;             // 0..1 (64-px tile within block)
        int c16  = f >> 2, ct = f & 3;
        int li   = l & 31, h2 = l >> 5;
        const f16* src = &Vl[(ct*32 + li)*140 + ktl*64 + c16*16 + 4*h2];
        f16x4v lo = *(const f16x4v*)&src[0];
        f16x4v hi = *(const f16x4v*)&src[8];
        f16x8 v8;
        #pragma unroll
        for (int i = 0; i < 4; i++) { v8[i] = lo[i]; v8[4+i] = hi[i]; }
        int ktg = pt*2 + ktl;              // 64-key tile index
        *(f16x8*)&Vf[((((size_t)b*64 + ktg)*16 + c16*4 + ct)*64 + l)*8] = v8;
    }
}

// ---------------------------------------------------------------------------
// Attention r20 = r19 (T15 pipeline) MINUS s_setprio. Two container failures
// on the r19 binary; only construct unique to it was the setprio builtin --
// removed to isolate. Schedule (the actual theory under test) unchanged:
//   StN = QK(t+2) MFMAs (issue first)
//   K(t+4) prefetch; partner-P(t) read (4 b128)
//   PV(t) 16 MFMAs + V(t+2) prefetch
//   exp StN -> po(t+2); write to Pex   <- VALU runs under PV's MFMA drain
//   __syncthreads()
// St(t+2) (32 regs) is the ONLY value extended across PV. Own-P in rotating
// poA/poB (static indices, manual 2-unroll); partner-P from LDS as in r10.
// Live-set est ~205 < 256. Spill canary: FETCH/WRITE bloat.
// ---------------------------------------------------------------------------
__global__ __launch_bounds__(256, 2)
void attn_kernel(const f16* __restrict__ Qt, const f16* __restrict__ Kt,
                 const f16* __restrict__ Vf, float* __restrict__ out)
{
    __shared__ __align__(16) unsigned char lds_raw[53504];
    // main loop:  Pex [4 waves][2 buf][4 kc][64 lanes][16B] = 32 KB at 0
    // epilogue:   combine regions 2 x 9216 at 0; ls_inv f32[64] at 18432;
    //             Tb f32[128][68] at 18688 (all alias Pex; phases barriered)

    const int tid  = threadIdx.x;
    const int lane = tid & 63;
    const int w    = tid >> 6;
    const int cp   = w & 1;            // channel pair + q-tile ownership
    const int kh   = w >> 1;           // key half: kt = kh (mod 2)
    const int b    = blockIdx.x & 7;
    const int qt   = blockIdx.x >> 3;  // 0..63
    const int q0   = qt*64;
    const int n32  = lane & 31;
    const int half = lane >> 5;

    const f16* vb = Vf + (size_t)b*64*16*512;
    const f16* kb = Kt + (size_t)b*NN*16;
    // own q-tile only: A (q0..q0+31) if cp==0, B (q0+32..) if cp==1
    const f16x8 qf = *(const f16x8*)&Qt[((size_t)b*NN + q0 + cp*32 + n32)*16 + half*8];

    f32x16 ofA[2], ofB[2];
    #pragma unroll
    for (int c = 0; c < 2; c++) { ofA[c] = (f32x16)0.0f; ofB[c] = (f32x16)0.0f; }
    float ps[4] = {0.f, 0.f, 0.f, 0.f};

    // prime: K(kh) + this wave's 8 V fragments for kt = kh
    f16x8 kf0 = *(const f16x8*)&kb[((size_t)kh*64 + n32)*16 + half*8];
    f16x8 kf1 = *(const f16x8*)&kb[((size_t)kh*64 + 32 + n32)*16 + half*8];
    f16x8 vpf[8];
    {
        const f16* vt = vb + (size_t)kh*8192;
        #pragma unroll
        for (int kc = 0; kc < 4; kc++)
            #pragma unroll
            for (int j = 0; j < 2; j++)
                vpf[kc*2+j] = *(const f16x8*)&vt[((size_t)(kc*4 + 2*cp + j)*64 + lane)*8];
    }

    f16* Pex = (f16*)lds_raw;
    f16x8 poA[4], poB[4];

    // ---- prologue: P(kh) -> poA, write slot (w, buf0) ----
    {
        f32x16 St0 = __builtin_amdgcn_mfma_f32_32x32x16_f16(kf0, qf, (f32x16)(-SHIFT), 0, 0, 0);
        f32x16 St1 = __builtin_amdgcn_mfma_f32_32x32x16_f16(kf1, qf, (f32x16)(-SHIFT), 0, 0, 0);
        kf0 = *(const f16x8*)&kb[((size_t)(kh+2)*64 + n32)*16 + half*8];
        kf1 = *(const f16x8*)&kb[((size_t)(kh+2)*64 + 32 + n32)*16 + half*8];
        #pragma unroll
        for (int g = 0; g < 16; g++) {
            float e0 = EXP2(St0[g]); ps[g & 3] += e0; poA[(g >> 3)][g & 7]     = (f16)e0;
            float e1 = EXP2(St1[g]); ps[g & 3] += e1; poA[2 + (g >> 3)][g & 7] = (f16)e1;
        }
        f16* wr = &Pex[((size_t)(w*2 + 0)*4*64 + lane)*8];
        #pragma unroll
        for (int kc = 0; kc < 4; kc++) *(f16x8*)&wr[kc*512] = poA[kc];
    }
    __syncthreads();

#define PV_CORE(PA, PB, VTN)                                                          \
        _Pragma("unroll")                                                             \
        for (int kc = 0; kc < 4; kc++) {                                              \
            _Pragma("unroll")                                                         \
            for (int j = 0; j < 2; j++) {                                             \
                const int ii = kc*2 + j;                                              \
                f16x8 vc = vpf[ii];                                                   \
                vpf[ii] = *(const f16x8*)&(VTN)[((size_t)(kc*4 + 2*cp + j)*64 + lane)*8]; \
                ofA[j] = __builtin_amdgcn_mfma_f32_32x32x16_f16(PA[kc], vc, ofA[j], 0, 0, 0); \
                ofB[j] = __builtin_amdgcn_mfma_f32_32x32x16_f16(PB[kc], vc, ofB[j], 0, 0, 0); \
            }                                                                         \
        }

    // STEP(T, POC, PON, RB): PV(T) with own POC + partner from buf RB;
    // pipeline: QK(T+2) issued FIRST, exp'd AFTER PV into PON -> buf RB^1.
#define STEP(T, POC, PON, RB)                                                         \
    {                                                                                 \
        f32x16 St0 = __builtin_amdgcn_mfma_f32_32x32x16_f16(kf0, qf, (f32x16)(-SHIFT), 0, 0, 0); \
        f32x16 St1 = __builtin_amdgcn_mfma_f32_32x32x16_f16(kf1, qf, (f32x16)(-SHIFT), 0, 0, 0); \
        {                                                                             \
            int tl = (T) + 4; if (tl >= NN/64) tl = (T) + 2;                          \
            kf0 = *(const f16x8*)&kb[((size_t)tl*64 + n32)*16 + half*8];              \
            kf1 = *(const f16x8*)&kb[((size_t)tl*64 + 32 + n32)*16 + half*8];         \
        }                                                                             \
        f16x8 pq[4];                                                                  \
        {                                                                             \
            const f16* rd = &Pex[((size_t)((w^1)*2 + (RB))*4*64 + lane)*8];           \
            _Pragma("unroll")                                                         \
            for (int kc = 0; kc < 4; kc++) pq[kc] = *(const f16x8*)&rd[kc*512];       \
        }                                                                             \
        const f16* vtn = vb + (size_t)((T)+2)*8192;                                   \
        if (cp == 0) { PV_CORE(POC, pq, vtn) } else { PV_CORE(pq, POC, vtn) }         \
        _Pragma("unroll")                                                             \
        for (int g = 0; g < 16; g++) {                                                \
            float e0 = EXP2(St0[g]); ps[g & 3] += e0; PON[(g >> 3)][g & 7]     = (f16)e0; \
            float e1 = EXP2(St1[g]); ps[g & 3] += e1; PON[2 + (g >> 3)][g & 7] = (f16)e1; \
        }                                                                             \
        {                                                                             \
            f16* wr = &Pex[((size_t)(w*2 + ((RB)^1))*4*64 + lane)*8];                 \
            _Pragma("unroll")                                                         \
            for (int kc = 0; kc < 4; kc++) *(f16x8*)&wr[kc*512] = PON[kc];            \
        }                                                                             \
        __syncthreads();                                                              \
    }

    // 31 steps cover PV(kh)..PV(kh+60), preparing P up to kh+62
    for (int it = 0; it < 15; ++it) {
        const int kt = kh + it*4;
        STEP(kt,     poA, poB, 0)
        STEP(kt + 2, poB, poA, 1)
    }
    STEP(kh + 60, poA, poB, 0)
    // final: PV(kh+62) with poB + partner from buf1, no prefetch
    {
        f16x8 pq[4];
        const f16* rd = &Pex[((size_t)((w^1)*2 + 1)*4*64 + lane)*8];
        #pragma unroll
        for (int kc = 0; kc < 4; kc++) pq[kc] = *(const f16x8*)&rd[kc*512];
        #pragma unroll
        for (int kc = 0; kc < 4; kc++) {
            #pragma unroll
            for (int j = 0; j < 2; j++) {
                f16x8 vc = vpf[kc*2+j];
                if (cp == 0) {
                    ofA[j] = __builtin_amdgcn_mfma_f32_32x32x16_f16(poB[kc], vc, ofA[j], 0, 0, 0);
                    ofB[j] = __builtin_amdgcn_mfma_f32_32x32x16_f16(pq[kc],  vc, ofB[j], 0, 0, 0);
                } else {
                    ofA[j] = __builtin_amdgcn_mfma_f32_32x32x16_f16(pq[kc],  vc, ofA[j], 0, 0, 0);
                    ofB[j] = __builtin_amdgcn_mfma_f32_32x32x16_f16(poB[kc], vc, ofB[j], 0, 0, 0);
                }
            }
        }
    }
#undef STEP
#undef PV_CORE

    // per-lane softmax denominator for own q-tile (this wave's key half)
    float ls = (ps[0] + ps[1]) + (ps[2] + ps[3]);
    ls += __shfl_xor(ls, 32);

    // ---- combine the 2-way key split (wave pairs (0,2) and (1,3)) ----
    __syncthreads();
    if (w >= 2) {
        unsigned char* base = lds_raw + (size_t)cp*9216 + (size_t)lane*144;
        #pragma unroll
        for (int a = 0; a < 4; a++) {        // a = qtsel*2 + ctl
            #pragma unroll
            for (int h = 0; h < 2; h++) {
                f16x8 t;
                #pragma unroll
                for (int jj = 0; jj < 8; jj++)
                    t[jj] = (f16)((a < 2 ? ofA[a & 1] : ofB[a & 1])[h*8 + jj]);
                *(f16x8*)(base + a*32 + h*16) = t;
            }
        }
        *(float*)(base + 128) = ls;          // own q-tile's denominator partial
    }
    __syncthreads();
    if (w < 2) {
        unsigned char* base = lds_raw + (size_t)cp*9216 + (size_t)lane*144;
        #pragma unroll
        for (int a = 0; a < 4; a++) {
            #pragma unroll
            for (int h = 0; h < 2; h++) {
                f16x8 t = *(const f16x8*)(base + a*32 + h*16);
                #pragma unroll
                for (int jj = 0; jj < 8; jj++) {
                    float v = (float)t[jj];
                    if (a < 2) ofA[a & 1][h*8 + jj] += v;
                    else       ofB[a & 1][h*8 + jj] += v;
                }
            }
        }
        ls += *(const float*)(base + 128);
        // lead wave (0,cp) now has the full denominator for q-tile cp
        float* ls_inv = (float*)(lds_raw + 18432);
        if (lane < 32) ls_inv[cp*32 + n32] = 1.f / ls;
    }
    __syncthreads();

    // normalize + transpose into Tb[c][q] (waves 0,1 own 64 channels each)
    if (w < 2) {
        const float* ls_inv = (const float*)(lds_raw + 18432);
        float* Tb = (float*)(lds_raw + 18688);
        #pragma unroll
        for (int qts = 0; qts < 2; qts++) {
            #pragma unroll
            for (int j = 0; j < 4; j++) {
                f32x4v iv = *(const f32x4v*)&ls_inv[qts*32 + 8*j + 4*half];
                #pragma unroll
                for (int ctl = 0; ctl < 2; ctl++) {
                    const int c = (2*cp + ctl)*32 + n32;
                    f32x4v o;
                    #pragma unroll
                    for (int e = 0; e < 4; e++)
                        o[e] = (qts ? ofB[ctl] : ofA[ctl])[4*j + e] * iv[e];
                    *(f32x4v*)&Tb[(size_t)c*68 + qts*32 + 8*j + 4*half] = o;
                }
            }
        }
    }
    __syncthreads();
    {
        const float* Tb = (const float*)(lds_raw + 18688);
        #pragma unroll
        for (int it = 0; it < 8; it++) {
            int idx = it*256 + tid;
            int c = idx >> 4, qg = idx & 15;
            f32x4v v = *(const f32x4v*)&Tb[(size_t)c*68 + qg*4];
            // non-temporal: keep the 16 MB output stream out of L2
            __builtin_nontemporal_store(v,
                (f32x4v*)&out[((size_t)b*CC + c)*NN + q0 + qg*4]);
        }
    }
}

extern "C" void kernel_launch(void* const* d_in, const int* in_sizes, int n_in,
                              void* d_out, int out_size, void* d_ws, size_t ws_size,
                              hipStream_t stream) {
    const float* x  = (const float*)d_in[0];
    const float* Wq = (const float*)d_in[1];
    const float* bq = (const float*)d_in[2];
    const float* Wk = (const float*)d_in[3];
    const float* bk = (const float*)d_in[4];
    const float* Wv = (const float*)d_in[5];
    const float* bv = (const float*)d_in[6];
    float* out = (float*)d_out;

    // workspace: Qt,Kt f16 [B][N][16] (1MB each), Vf f16 sigma-fragments (8MB)
    f16* Qw = (f16*)d_ws;
    f16* Kw = Qw + (size_t)BB*NN*16;
    f16* Vw = Kw + (size_t)BB*NN*16;
    unsigned char* tail = (unsigned char*)d_out + (size_t)out_size*4 - WF_BYTES;
    f16*   Wf    = (f16*)tail;
    float* biasS = (float*)(tail + 49152);

    hipLaunchKernelGGL(prep_kernel, dim3(10), dim3(256), 0, stream,
                       Wq, bq, Wk, bk, Wv, bv, Wf, biasS);
    hipLaunchKernelGGL(proj_kernel, dim3(256), dim3(256), 0, stream,
                       x, Wf, biasS, Qw, Kw, Vw);
    hipLaunchKernelGGL(attn_kernel, dim3(512), dim3(256), 0, stream,
                       Qw, Kw, Vw, out);
}

// Round 14
// 132.325 us; speedup vs baseline: 1.2357x; 1.2357x over previous
//
#include <hip/hip_runtime.h>
#include <math.h>

#define BB 8
#define CC 128
#define NN 4096   // W*H

typedef _Float16 f16;
typedef _Float16 f16x4v __attribute__((ext_vector_type(4)));
typedef _Float16 f16x8 __attribute__((ext_vector_type(8)));
typedef float f32x4v __attribute__((ext_vector_type(4)));
typedef float f32x16 __attribute__((ext_vector_type(16)));

#if __has_builtin(__builtin_amdgcn_exp2f)
#define EXP2(x) __builtin_amdgcn_exp2f(x)
#else
#define EXP2(x) __expf((x)*0.69314718056f)
#endif

// Q rows pre-scaled by 0.25*log2(e): softmax exp is one native v_exp_f32;
// the -SHIFT bias rides in the MFMA C operand.
#define QSCALE 0.360673760222f   // 0.25 * log2(e)
#define SHIFT  5.770780163555f   // 4.0 * log2(e)

// Wf scratch lives in the tail of d_out (attn rewrites d_out afterwards).
#define WF_BYTES 65536

// ---------------------------------------------------------------------------
// prep: stack Wq*QSCALE (rows 0-15), Wk (16-31), Wv (32-159) as f16 in
// 32x32x16 A-fragment order. biasS f32[160] likewise stacked.
// ---------------------------------------------------------------------------
__global__ __launch_bounds__(256)
void prep_kernel(const float* __restrict__ Wq, const float* __restrict__ bq,
                 const float* __restrict__ Wk, const float* __restrict__ bk,
                 const float* __restrict__ Wv, const float* __restrict__ bv,
                 f16* __restrict__ Wf, float* __restrict__ biasS)
{
    const int tg = blockIdx.x*256 + threadIdx.x;   // 0..2559
    if (tg < 2560) {
        const int mt = tg >> 9, ks = (tg >> 6) & 7, l = tg & 63;
        const int n32 = l & 31, h = l >> 5;
        const int r = mt*32 + n32;
        f16x8 v8;
        #pragma unroll
        for (int i = 0; i < 8; i++) {
            int c = ks*16 + 8*h + i;
            float wv_;
            if (r < 16)      wv_ = QSCALE * Wq[r*CC + c];
            else if (r < 32) wv_ = Wk[(r-16)*CC + c];
            else             wv_ = Wv[(r-32)*CC + c];
            v8[i] = (f16)wv_;
        }
        *(f16x8*)&Wf[(size_t)tg*8] = v8;
    }
    if (blockIdx.x == 0 && threadIdx.x < 160) {
        int r = threadIdx.x;
        biasS[r] = r < 16 ? QSCALE*bq[r] : (r < 32 ? bk[r-16] : bv[r-32]);
    }
}

// ---------------------------------------------------------------------------
// proj r21: ONE change vs the r10-era proj -- x loads are PLAIN (cached),
// not __builtin_nontemporal_load. Theory: the stable ~75us non-attn residue
// is mostly proj running ~10x over its ~5us roofline; NT forces the
// L2/L3-bypass streaming path on 1M loads of data the harness just wrote
// (cache-resident), at 1 block/CU = fully exposed latency. x is read ONCE,
// so the original "keep L2 clean" rationale cost more than it saved.
// Everything else identical: grid 256 (b = bx&7, pt = bx>>3), 4 waves,
// 40 MFMAs/wave, Qt/Kt pixel-major epilogue, sigma-ordered Vf:
//   Vf[b][kt64][frag=kc*4+ct][l][i] =
//     V[c=ct*32+(l&31)][key=kt64*64 + kc*16 + (i&3)+8*(i>>2)+4*(l>>5)]
// ---------------------------------------------------------------------------
__global__ __launch_bounds__(256)
void proj_kernel(const float* __restrict__ x, const f16* __restrict__ Wf,
                 const float* __restrict__ biasS,
                 f16* __restrict__ Qt, f16* __restrict__ Kt, f16* __restrict__ Vf)
{
    __shared__ __align__(16) f16 Vl[CC*140];   // 35 KB, stride 140 halfs

    const int tid  = threadIdx.x;
    const int lane = tid & 63;
    const int wv   = tid >> 6;
    const int b    = blockIdx.x & 7;
    const int pt   = blockIdx.x >> 3;      // 0..31
    const int n32  = lane & 31;
    const int half = lane >> 5;
    const int p    = pt*128 + wv*32 + n32;

    const float* xp = x + (size_t)b*CC*NN + p;
    f16x8 xf[8];
    #pragma unroll
    for (int ks = 0; ks < 8; ks++) {
        float xv[8];
        #pragma unroll
        for (int i = 0; i < 8; i++)
            xv[i] = xp[(size_t)(ks*16 + 8*half + i)*NN];   // plain cached load
        #pragma unroll
        for (int i = 0; i < 8; i++) xf[ks][i] = (f16)xv[i];
    }

    f32x16 acc[5];
    #pragma unroll
    for (int mt = 0; mt < 5; mt++) acc[mt] = (f32x16)0.0f;
    #pragma unroll
    for (int ks = 0; ks < 8; ks++) {
        #pragma unroll
        for (int mt = 0; mt < 5; mt++) {
            f16x8 wfr = *(const f16x8*)&Wf[((size_t)(mt*8 + ks)*64 + lane)*8];
            acc[mt] = __builtin_amdgcn_mfma_f32_32x32x16_f16(wfr, xf[ks], acc[mt], 0, 0, 0);
        }
    }

    #pragma unroll
    for (int mt = 0; mt < 5; mt++) {
        #pragma unroll
        for (int q = 0; q < 4; q++) {
            float4 b4 = *(const float4*)&biasS[mt*32 + q*8 + 4*half];
            acc[mt][q*4+0] += b4.x; acc[mt][q*4+1] += b4.y;
            acc[mt][q*4+2] += b4.z; acc[mt][q*4+3] += b4.w;
        }
    }

    // mt0: rows 0-15 = Q, 16-31 = K
    {
        size_t qkoff = ((size_t)b*NN + p)*16;
        f16x4v s0, s1, s2, s3;
        #pragma unroll
        for (int i = 0; i < 4; i++) {
            s0[i] = (f16)acc[0][i];    s1[i] = (f16)acc[0][4+i];
            s2[i] = (f16)acc[0][8+i];  s3[i] = (f16)acc[0][12+i];
        }
        *(f16x4v*)&Qt[qkoff + 4*half]     = s0;
        *(f16x4v*)&Qt[qkoff + 8 + 4*half] = s1;
        *(f16x4v*)&Kt[qkoff + 4*half]     = s2;
        *(f16x4v*)&Kt[qkoff + 8 + 4*half] = s3;
    }

    // mt1-4: V channels -> LDS [c][local pixel]
    #pragma unroll
    for (int mt = 1; mt < 5; mt++) {
        #pragma unroll
        for (int g = 0; g < 16; g++) {
            int c = (mt-1)*32 + (g & 3) + 8*(g >> 2) + 4*half;
            Vl[c*140 + wv*32 + n32] = (f16)acc[mt][g];
        }
    }
    __syncthreads();

    // sigma-ordered Vf writeout
    #pragma unroll
    for (int pass = 0; pass < 8; pass++) {
        int item = pass*256 + tid;
        int l    = item & 63;
        int f    = (item >> 6) & 15;       // kc*4 + ct
        int ktl  = item >> 10;             // 0..1 (64-px tile within block)
        int c16  = f >> 2, ct = f & 3;
        int li   = l & 31, h2 = l >> 5;
        const f16* src = &Vl[(ct*32 + li)*140 + ktl*64 + c16*16 + 4*h2];
        f16x4v lo = *(const f16x4v*)&src[0];
        f16x4v hi = *(const f16x4v*)&src[8];
        f16x8 v8;
        #pragma unroll
        for (int i = 0; i < 4; i++) { v8[i] = lo[i]; v8[4+i] = hi[i]; }
        int ktg = pt*2 + ktl;              // 64-key tile index
        *(f16x8*)&Vf[((((size_t)b*64 + ktg)*16 + c16*4 + ct)*64 + l)*8] = v8;
    }
}

// ---------------------------------------------------------------------------
// Attention r10 (champion, 53.4us, VGPR 108, zero spill) -- byte-exact.
// Eleven schedule/traffic/occupancy variants (r8-r20) all bounced off the
// ~53us envelope; T15-style exp-under-PV spills (r12, r20 twins). This
// decomposition's attn floor. Grid 512 (b = bx&7, qt = bx>>3 -> 64q),
// block 256 = 4 waves: cp = w&1 (channel pair + q-tile owner), kh = w>>1
// (key half). Per iter: QK^T+exp for own q-tile only, P-exchange via
// double-buffered LDS, PV for both q-tiles (each V frag feeds 2 MFMAs).
// ---------------------------------------------------------------------------
__global__ __launch_bounds__(256, 2)
void attn_kernel(const f16* __restrict__ Qt, const f16* __restrict__ Kt,
                 const f16* __restrict__ Vf, float* __restrict__ out)
{
    __shared__ __align__(16) unsigned char lds_raw[53504];
    // main loop:  Pex [4 waves][2 buf][4 kc][64 lanes][16B] = 32 KB at 0
    // epilogue:   combine regions 2 x 9216 at 0; ls_inv f32[64] at 18432;
    //             Tb f32[128][68] at 18688 (all alias Pex; phases barriered)

    const int tid  = threadIdx.x;
    const int lane = tid & 63;
    const int w    = tid >> 6;
    const int cp   = w & 1;            // channel pair + q-tile ownership
    const int kh   = w >> 1;           // key half: kt = kh (mod 2)
    const int b    = blockIdx.x & 7;
    const int qt   = blockIdx.x >> 3;  // 0..63
    const int q0   = qt*64;
    const int n32  = lane & 31;
    const int half = lane >> 5;

    const f16* vb = Vf + (size_t)b*64*16*512;
    const f16* kb = Kt + (size_t)b*NN*16;
    // own q-tile only: A (q0..q0+31) if cp==0, B (q0+32..) if cp==1
    const f16x8 qf = *(const f16x8*)&Qt[((size_t)b*NN + q0 + cp*32 + n32)*16 + half*8];

    f32x16 ofA[2], ofB[2];
    #pragma unroll
    for (int c = 0; c < 2; c++) { ofA[c] = (f32x16)0.0f; ofB[c] = (f32x16)0.0f; }
    float ps[4] = {0.f, 0.f, 0.f, 0.f};

    // prime the pipeline: K + this wave's 8 V fragments for kt = kh
    f16x8 kf0 = *(const f16x8*)&kb[((size_t)kh*64 + n32)*16 + half*8];
    f16x8 kf1 = *(const f16x8*)&kb[((size_t)kh*64 + 32 + n32)*16 + half*8];
    f16x8 vpf[8];
    {
        const f16* vt = vb + (size_t)kh*8192;
        #pragma unroll
        for (int kc = 0; kc < 4; kc++)
            #pragma unroll
            for (int j = 0; j < 2; j++)
                vpf[kc*2+j] = *(const f16x8*)&vt[((size_t)(kc*4 + 2*cp + j)*64 + lane)*8];
    }

    f16* Pex = (f16*)lds_raw;
    int pb = 0;

    for (int kt = kh; kt < NN/64; kt += 2) {
        const int ktn = (kt + 2 < NN/64) ? kt + 2 : kt;
        f16x8 kf0n = *(const f16x8*)&kb[((size_t)ktn*64 + n32)*16 + half*8];
        f16x8 kf1n = *(const f16x8*)&kb[((size_t)ktn*64 + 32 + n32)*16 + half*8];

        // own q-tile: S^T = K * qf, P = 2^(S - SHIFT)
        f16x8 po[4];
        {
            f32x16 St0 = __builtin_amdgcn_mfma_f32_32x32x16_f16(kf0, qf, (f32x16)(-SHIFT), 0, 0, 0);
            f32x16 St1 = __builtin_amdgcn_mfma_f32_32x32x16_f16(kf1, qf, (f32x16)(-SHIFT), 0, 0, 0);
            #pragma unroll
            for (int g = 0; g < 16; g++) {
                float e0 = EXP2(St0[g]); ps[g & 3] += e0; po[(g >> 3)][g & 7]     = (f16)e0;
                float e1 = EXP2(St1[g]); ps[g & 3] += e1; po[2 + (g >> 3)][g & 7] = (f16)e1;
            }
        }

        // ---- P exchange with partner wave (w^1): same kh, other q-tile ----
        {
            f16* wr = &Pex[((size_t)(w*2 + pb)*4*64 + lane)*8];
            #pragma unroll
            for (int kc = 0; kc < 4; kc++)
                *(f16x8*)&wr[kc*512] = po[kc];
        }
        __syncthreads();
        f16x8 pq[4];
        {
            const f16* rd = &Pex[((size_t)((w^1)*2 + pb)*4*64 + lane)*8];
            #pragma unroll
            for (int kc = 0; kc < 4; kc++)
                pq[kc] = *(const f16x8*)&rd[kc*512];
        }

        const f16* vtn = vb + (size_t)ktn*8192;
#define PV_BLOCK(PA, PB)                                                              \
        _Pragma("unroll")                                                             \
        for (int kc = 0; kc < 4; kc++) {                                              \
            _Pragma("unroll")                                                         \
            for (int j = 0; j < 2; j++) {                                             \
                const int ii = kc*2 + j;                                              \
                f16x8 vc = vpf[ii];                                                   \
                vpf[ii] = *(const f16x8*)&vtn[((size_t)(kc*4 + 2*cp + j)*64 + lane)*8]; \
                ofA[j] = __builtin_amdgcn_mfma_f32_32x32x16_f16(PA[kc], vc, ofA[j], 0, 0, 0); \
                ofB[j] = __builtin_amdgcn_mfma_f32_32x32x16_f16(PB[kc], vc, ofB[j], 0, 0, 0); \
            }                                                                         \
        }
        if (cp == 0) { PV_BLOCK(po, pq) }
        else         { PV_BLOCK(pq, po) }
#undef PV_BLOCK

        kf0 = kf0n; kf1 = kf1n; pb ^= 1;
    }

    // per-lane softmax denominator for own q-tile (this wave's key half)
    float ls = (ps[0] + ps[1]) + (ps[2] + ps[3]);
    ls += __shfl_xor(ls, 32);

    // ---- combine the 2-way key split (wave pairs (0,2) and (1,3)) ----
    __syncthreads();
    if (w >= 2) {
        unsigned char* base = lds_raw + (size_t)cp*9216 + (size_t)lane*144;
        #pragma unroll
        for (int a = 0; a < 4; a++) {        // a = qtsel*2 + ctl
            #pragma unroll
            for (int h = 0; h < 2; h++) {
                f16x8 t;
                #pragma unroll
                for (int jj = 0; jj < 8; jj++)
                    t[jj] = (f16)((a < 2 ? ofA[a & 1] : ofB[a & 1])[h*8 + jj]);
                *(f16x8*)(base + a*32 + h*16) = t;
            }
        }
        *(float*)(base + 128) = ls;          // own q-tile's denominator partial
    }
    __syncthreads();
    if (w < 2) {
        unsigned char* base = lds_raw + (size_t)cp*9216 + (size_t)lane*144;
        #pragma unroll
        for (int a = 0; a < 4; a++) {
            #pragma unroll
            for (int h = 0; h < 2; h++) {
                f16x8 t = *(const f16x8*)(base + a*32 + h*16);
                #pragma unroll
                for (int jj = 0; jj < 8; jj++) {
                    float v = (float)t[jj];
                    if (a < 2) ofA[a & 1][h*8 + jj] += v;
                    else       ofB[a & 1][h*8 + jj] += v;
                }
            }
        }
        ls += *(const float*)(base + 128);
        // lead wave (0,cp) now has the full denominator for q-tile cp
        float* ls_inv = (float*)(lds_raw + 18432);
        if (lane < 32) ls_inv[cp*32 + n32] = 1.f / ls;
    }
    __syncthreads();

    // normalize + transpose into Tb[c][q] (waves 0,1 own 64 channels each)
    if (w < 2) {
        const float* ls_inv = (const float*)(lds_raw + 18432);
        float* Tb = (float*)(lds_raw + 18688);
        #pragma unroll
        for (int qts = 0; qts < 2; qts++) {
            #pragma unroll
            for (int j = 0; j < 4; j++) {
                f32x4v iv = *(const f32x4v*)&ls_inv[qts*32 + 8*j + 4*half];
                #pragma unroll
                for (int ctl = 0; ctl < 2; ctl++) {
                    const int c = (2*cp + ctl)*32 + n32;
                    f32x4v o;
                    #pragma unroll
                    for (int e = 0; e < 4; e++)
                        o[e] = (qts ? ofB[ctl] : ofA[ctl])[4*j + e] * iv[e];
                    *(f32x4v*)&Tb[(size_t)c*68 + qts*32 + 8*j + 4*half] = o;
                }
            }
        }
    }
    __syncthreads();
    {
        const float* Tb = (const float*)(lds_raw + 18688);
        #pragma unroll
        for (int it = 0; it < 8; it++) {
            int idx = it*256 + tid;
            int c = idx >> 4, qg = idx & 15;
            f32x4v v = *(const f32x4v*)&Tb[(size_t)c*68 + qg*4];
            // non-temporal: keep the 16 MB output stream out of L2
            __builtin_nontemporal_store(v,
                (f32x4v*)&out[((size_t)b*CC + c)*NN + q0 + qg*4]);
        }
    }
}

extern "C" void kernel_launch(void* const* d_in, const int* in_sizes, int n_in,
                              void* d_out, int out_size, void* d_ws, size_t ws_size,
                              hipStream_t stream) {
    const float* x  = (const float*)d_in[0];
    const float* Wq = (const float*)d_in[1];
    const float* bq = (const float*)d_in[2];
    const float* Wk = (const float*)d_in[3];
    const float* bk = (const float*)d_in[4];
    const float* Wv = (const float*)d_in[5];
    const float* bv = (const float*)d_in[6];
    float* out = (float*)d_out;

    // workspace: Qt,Kt f16 [B][N][16] (1MB each), Vf f16 sigma-fragments (8MB)
    f16* Qw = (f16*)d_ws;
    f16* Kw = Qw + (size_t)BB*NN*16;
    f16* Vw = Kw + (size_t)BB*NN*16;
    unsigned char* tail = (unsigned char*)d_out + (size_t)out_size*4 - WF_BYTES;
    f16*   Wf    = (f16*)tail;
    float* biasS = (float*)(tail + 49152);

    hipLaunchKernelGGL(prep_kernel, dim3(10), dim3(256), 0, stream,
                       Wq, bq, Wk, bk, Wv, bv, Wf, biasS);
    hipLaunchKernelGGL(proj_kernel, dim3(256), dim3(256), 0, stream,
                       x, Wf, biasS, Qw, Kw, Vw);
    hipLaunchKernelGGL(attn_kernel, dim3(512), dim3(256), 0, stream,
                       Qw, Kw, Vw, out);
}

// Round 16
// 131.748 us; speedup vs baseline: 1.2411x; 1.0044x over previous
//
#include <hip/hip_runtime.h>
#include <math.h>

#define BB 8
#define CC 128
#define NN 4096   // W*H

typedef _Float16 f16;
typedef _Float16 f16x2 __attribute__((ext_vector_type(2)));
typedef _Float16 f16x4v __attribute__((ext_vector_type(4)));
typedef _Float16 f16x8 __attribute__((ext_vector_type(8)));
typedef float f32x4v __attribute__((ext_vector_type(4)));
typedef float f32x16 __attribute__((ext_vector_type(16)));
typedef int i32x4 __attribute__((ext_vector_type(4)));

#if __has_builtin(__builtin_amdgcn_exp2f)
#define EXP2(x) __builtin_amdgcn_exp2f(x)
#else
#define EXP2(x) __expf((x)*0.69314718056f)
#endif

#if __has_builtin(__builtin_amdgcn_cvt_pkrtz) && __has_builtin(__builtin_amdgcn_fdot2)
#define CVTPK(a,b)    __builtin_amdgcn_cvt_pkrtz((a),(b))
#define FDOT2(pk,acc) __builtin_amdgcn_fdot2((pk), one2_, (acc), false)
#else
static __device__ inline f16x2 cvtpk_fb(float a, float b){ f16x2 r; r[0]=(f16)a; r[1]=(f16)b; return r; }
#define CVTPK(a,b)    cvtpk_fb((a),(b))
#define FDOT2(pk,acc) ((acc) + (float)(pk)[0] + (float)(pk)[1])
#endif

// Q rows pre-scaled by 0.25*log2(e): softmax exp is one native v_exp_f32;
// the -SHIFT bias rides in the MFMA C operand.
#define QSCALE 0.360673760222f   // 0.25 * log2(e)
#define SHIFT  5.770780163555f   // 4.0 * log2(e)

// Wf scratch lives in the tail of d_out (attn rewrites d_out afterwards).
#define WF_BYTES 65536

// ---------------------------------------------------------------------------
// prep: stack Wq*QSCALE (rows 0-15), Wk (16-31), Wv (32-159) as f16 in
// 32x32x16 A-fragment order. biasS f32[160] likewise stacked.
// ---------------------------------------------------------------------------
__global__ __launch_bounds__(256)
void prep_kernel(const float* __restrict__ Wq, const float* __restrict__ bq,
                 const float* __restrict__ Wk, const float* __restrict__ bk,
                 const float* __restrict__ Wv, const float* __restrict__ bv,
                 f16* __restrict__ Wf, float* __restrict__ biasS)
{
    const int tg = blockIdx.x*256 + threadIdx.x;   // 0..2559
    if (tg < 2560) {
        const int mt = tg >> 9, ks = (tg >> 6) & 7, l = tg & 63;
        const int n32 = l & 31, h = l >> 5;
        const int r = mt*32 + n32;
        f16x8 v8;
        #pragma unroll
        for (int i = 0; i < 8; i++) {
            int c = ks*16 + 8*h + i;
            float wv_;
            if (r < 16)      wv_ = QSCALE * Wq[r*CC + c];
            else if (r < 32) wv_ = Wk[(r-16)*CC + c];
            else             wv_ = Wv[(r-32)*CC + c];
            v8[i] = (f16)wv_;
        }
        *(f16x8*)&Wf[(size_t)tg*8] = v8;
    }
    if (blockIdx.x == 0 && threadIdx.x < 160) {
        int r = threadIdx.x;
        biasS[r] = r < 16 ? QSCALE*bq[r] : (r < 32 ? bk[r-16] : bv[r-32]);
    }
}

// ---------------------------------------------------------------------------
// proj (r21: plain cached x loads -- NT bypass removed; kept, small win):
// grid 256 (b = bx&7, pt = bx>>3), 4 waves, 40 MFMAs/wave.
// Epilogue: Qt/Kt pixel-major; V via LDS -> sigma-ordered Vf:
//   Vf[b][kt64][frag=kc*4+ct][l][i] =
//     V[c=ct*32+(l&31)][key=kt64*64 + kc*16 + (i&3)+8*(i>>2)+4*(l>>5)]
// ---------------------------------------------------------------------------
__global__ __launch_bounds__(256)
void proj_kernel(const float* __restrict__ x, const f16* __restrict__ Wf,
                 const float* __restrict__ biasS,
                 f16* __restrict__ Qt, f16* __restrict__ Kt, f16* __restrict__ Vf)
{
    __shared__ __align__(16) f16 Vl[CC*140];   // 35 KB, stride 140 halfs

    const int tid  = threadIdx.x;
    const int lane = tid & 63;
    const int wv   = tid >> 6;
    const int b    = blockIdx.x & 7;
    const int pt   = blockIdx.x >> 3;      // 0..31
    const int n32  = lane & 31;
    const int half = lane >> 5;
    const int p    = pt*128 + wv*32 + n32;

    const float* xp = x + (size_t)b*CC*NN + p;
    f16x8 xf[8];
    #pragma unroll
    for (int ks = 0; ks < 8; ks++) {
        float xv[8];
        #pragma unroll
        for (int i = 0; i < 8; i++)
            xv[i] = xp[(size_t)(ks*16 + 8*half + i)*NN];   // plain cached load
        #pragma unroll
        for (int i = 0; i < 8; i++) xf[ks][i] = (f16)xv[i];
    }

    f32x16 acc[5];
    #pragma unroll
    for (int mt = 0; mt < 5; mt++) acc[mt] = (f32x16)0.0f;
    #pragma unroll
    for (int ks = 0; ks < 8; ks++) {
        #pragma unroll
        for (int mt = 0; mt < 5; mt++) {
            f16x8 wfr = *(const f16x8*)&Wf[((size_t)(mt*8 + ks)*64 + lane)*8];
            acc[mt] = __builtin_amdgcn_mfma_f32_32x32x16_f16(wfr, xf[ks], acc[mt], 0, 0, 0);
        }
    }

    #pragma unroll
    for (int mt = 0; mt < 5; mt++) {
        #pragma unroll
        for (int q = 0; q < 4; q++) {
            float4 b4 = *(const float4*)&biasS[mt*32 + q*8 + 4*half];
            acc[mt][q*4+0] += b4.x; acc[mt][q*4+1] += b4.y;
            acc[mt][q*4+2] += b4.z; acc[mt][q*4+3] += b4.w;
        }
    }

    // mt0: rows 0-15 = Q, 16-31 = K
    {
        size_t qkoff = ((size_t)b*NN + p)*16;
        f16x4v s0, s1, s2, s3;
        #pragma unroll
        for (int i = 0; i < 4; i++) {
            s0[i] = (f16)acc[0][i];    s1[i] = (f16)acc[0][4+i];
            s2[i] = (f16)acc[0][8+i];  s3[i] = (f16)acc[0][12+i];
        }
        *(f16x4v*)&Qt[qkoff + 4*half]     = s0;
        *(f16x4v*)&Qt[qkoff + 8 + 4*half] = s1;
        *(f16x4v*)&Kt[qkoff + 4*half]     = s2;
        *(f16x4v*)&Kt[qkoff + 8 + 4*half] = s3;
    }

    // mt1-4: V channels -> LDS [c][local pixel]
    #pragma unroll
    for (int mt = 1; mt < 5; mt++) {
        #pragma unroll
        for (int g = 0; g < 16; g++) {
            int c = (mt-1)*32 + (g & 3) + 8*(g >> 2) + 4*half;
            Vl[c*140 + wv*32 + n32] = (f16)acc[mt][g];
        }
    }
    __syncthreads();

    // sigma-ordered Vf writeout
    #pragma unroll
    for (int pass = 0; pass < 8; pass++) {
        int item = pass*256 + tid;
        int l    = item & 63;
        int f    = (item >> 6) & 15;       // kc*4 + ct
        int ktl  = item >> 10;             // 0..1 (64-px tile within block)
        int c16  = f >> 2, ct = f & 3;
        int li   = l & 31, h2 = l >> 5;
        const f16* src = &Vl[(ct*32 + li)*140 + ktl*64 + c16*16 + 4*h2];
        f16x4v lo = *(const f16x4v*)&src[0];
        f16x4v hi = *(const f16x4v*)&src[8];
        f16x8 v8;
        #pragma unroll
        for (int i = 0; i < 4; i++) { v8[i] = lo[i]; v8[4+i] = hi[i]; }
        int ktg = pt*2 + ktl;              // 64-key tile index
        *(f16x8*)&Vf[((((size_t)b*64 + ktg)*16 + c16*4 + ct)*64 + l)*8] = v8;
    }
}

// ---------------------------------------------------------------------------
// Attention r23 = r22 with the compile fix (CVTPK results held in `auto` --
// the builtin returns __fp16x2, which clang won't implicitly convert to a
// _Float16 vector; r14 used `auto` and compiled). Two levers under test:
//  1. lgkm-only main-loop barrier ("s_waitcnt lgkmcnt(0); s_barrier"):
//     __syncthreads drained vmcnt(0) each iter, force-completing V(t+2)/K
//     prefetches ~600cyc after issue -- the measured achieved-BW cap
//     (r8 barrier-free 16-deep: 20.6 TB/s; r10: 12.3). P-exchange only
//     needs LDS drained; this barrier passed correctness in r13/r14.
//  2. Packed exp epilogue: cvt_pkrtz pairs exps straight to f16 AND fdot2
//     folds the denominator from the packed value -- per-tile VALU shrinks
//     {32 exp + 32 add + 32 cvt}=96 -> {32 exp + 16 pk + 16 fdot2}=64.
// Everything else byte-identical to r10. Spill canary: FETCH/WRITE bloat.
// ---------------------------------------------------------------------------
__global__ __launch_bounds__(256, 2)
void attn_kernel(const f16* __restrict__ Qt, const f16* __restrict__ Kt,
                 const f16* __restrict__ Vf, float* __restrict__ out)
{
    __shared__ __align__(16) unsigned char lds_raw[53504];
    // main loop:  Pex [4 waves][2 buf][4 kc][64 lanes][16B] = 32 KB at 0
    // epilogue:   combine regions 2 x 9216 at 0; ls_inv f32[64] at 18432;
    //             Tb f32[128][68] at 18688 (all alias Pex; phases barriered)

    const int tid  = threadIdx.x;
    const int lane = tid & 63;
    const int w    = tid >> 6;
    const int cp   = w & 1;            // channel pair + q-tile ownership
    const int kh   = w >> 1;           // key half: kt = kh (mod 2)
    const int b    = blockIdx.x & 7;
    const int qt   = blockIdx.x >> 3;  // 0..63
    const int q0   = qt*64;
    const int n32  = lane & 31;
    const int half = lane >> 5;

    const f16* vb = Vf + (size_t)b*64*16*512;
    const f16* kb = Kt + (size_t)b*NN*16;
    // own q-tile only: A (q0..q0+31) if cp==0, B (q0+32..) if cp==1
    const f16x8 qf = *(const f16x8*)&Qt[((size_t)b*NN + q0 + cp*32 + n32)*16 + half*8];

    const auto one2_ = CVTPK(1.0f, 1.0f);

    f32x16 ofA[2], ofB[2];
    #pragma unroll
    for (int c = 0; c < 2; c++) { ofA[c] = (f32x16)0.0f; ofB[c] = (f32x16)0.0f; }
    float ps[4] = {0.f, 0.f, 0.f, 0.f};

    // prime the pipeline: K + this wave's 8 V fragments for kt = kh
    f16x8 kf0 = *(const f16x8*)&kb[((size_t)kh*64 + n32)*16 + half*8];
    f16x8 kf1 = *(const f16x8*)&kb[((size_t)kh*64 + 32 + n32)*16 + half*8];
    f16x8 vpf[8];
    {
        const f16* vt = vb + (size_t)kh*8192;
        #pragma unroll
        for (int kc = 0; kc < 4; kc++)
            #pragma unroll
            for (int j = 0; j < 2; j++)
                vpf[kc*2+j] = *(const f16x8*)&vt[((size_t)(kc*4 + 2*cp + j)*64 + lane)*8];
    }

    f16* Pex = (f16*)lds_raw;
    int pb = 0;

    for (int kt = kh; kt < NN/64; kt += 2) {
        const int ktn = (kt + 2 < NN/64) ? kt + 2 : kt;
        f16x8 kf0n = *(const f16x8*)&kb[((size_t)ktn*64 + n32)*16 + half*8];
        f16x8 kf1n = *(const f16x8*)&kb[((size_t)ktn*64 + 32 + n32)*16 + half*8];

        // own q-tile: S^T = K * qf, P = 2^(S - SHIFT), packed exp path
        f16x8 po[4];
        {
            f32x16 St0 = __builtin_amdgcn_mfma_f32_32x32x16_f16(kf0, qf, (f32x16)(-SHIFT), 0, 0, 0);
            f32x16 St1 = __builtin_amdgcn_mfma_f32_32x32x16_f16(kf1, qf, (f32x16)(-SHIFT), 0, 0, 0);
            i32x4 l0, h0, l1, h1;
            #pragma unroll
            for (int e = 0; e < 8; e++) {
                float a0 = EXP2(St0[2*e]), b0 = EXP2(St0[2*e+1]);
                auto p0 = CVTPK(a0, b0);
                ps[e & 1] = FDOT2(p0, ps[e & 1]);
                float a1 = EXP2(St1[2*e]), b1 = EXP2(St1[2*e+1]);
                auto p1 = CVTPK(a1, b1);
                ps[2 + (e & 1)] = FDOT2(p1, ps[2 + (e & 1)]);
                if (e < 4) { l0[e]   = __builtin_bit_cast(int, p0); l1[e]   = __builtin_bit_cast(int, p1); }
                else       { h0[e-4] = __builtin_bit_cast(int, p0); h1[e-4] = __builtin_bit_cast(int, p1); }
            }
            po[0] = __builtin_bit_cast(f16x8, l0);
            po[1] = __builtin_bit_cast(f16x8, h0);
            po[2] = __builtin_bit_cast(f16x8, l1);
            po[3] = __builtin_bit_cast(f16x8, h1);
        }

        // ---- P exchange with partner wave (w^1): same kh, other q-tile ----
        {
            f16* wr = &Pex[((size_t)(w*2 + pb)*4*64 + lane)*8];
            #pragma unroll
            for (int kc = 0; kc < 4; kc++)
                *(f16x8*)&wr[kc*512] = po[kc];
        }
        // LDS-only drain + barrier: V/K global prefetch stays in flight
        // (__syncthreads would force vmcnt(0), completing them early).
        asm volatile("s_waitcnt lgkmcnt(0)\n\ts_barrier" ::: "memory");
        f16x8 pq[4];
        {
            const f16* rd = &Pex[((size_t)((w^1)*2 + pb)*4*64 + lane)*8];
            #pragma unroll
            for (int kc = 0; kc < 4; kc++)
                pq[kc] = *(const f16x8*)&rd[kc*512];
        }

        const f16* vtn = vb + (size_t)ktn*8192;
#define PV_BLOCK(PA, PB)                                                              \
        _Pragma("unroll")                                                             \
        for (int kc = 0; kc < 4; kc++) {                                              \
            _Pragma("unroll")                                                         \
            for (int j = 0; j < 2; j++) {                                             \
                const int ii = kc*2 + j;                                              \
                f16x8 vc = vpf[ii];                                                   \
                vpf[ii] = *(const f16x8*)&vtn[((size_t)(kc*4 + 2*cp + j)*64 + lane)*8]; \
                ofA[j] = __builtin_amdgcn_mfma_f32_32x32x16_f16(PA[kc], vc, ofA[j], 0, 0, 0); \
                ofB[j] = __builtin_amdgcn_mfma_f32_32x32x16_f16(PB[kc], vc, ofB[j], 0, 0, 0); \
            }                                                                         \
        }
        if (cp == 0) { PV_BLOCK(po, pq) }
        else         { PV_BLOCK(pq, po) }
#undef PV_BLOCK

        kf0 = kf0n; kf1 = kf1n; pb ^= 1;
    }

    // per-lane softmax denominator for own q-tile (this wave's key half)
    float ls = (ps[0] + ps[1]) + (ps[2] + ps[3]);
    ls += __shfl_xor(ls, 32);

    // ---- combine the 2-way key split (wave pairs (0,2) and (1,3)) ----
    __syncthreads();
    if (w >= 2) {
        unsigned char* base = lds_raw + (size_t)cp*9216 + (size_t)lane*144;
        #pragma unroll
        for (int a = 0; a < 4; a++) {        // a = qtsel*2 + ctl
            #pragma unroll
            for (int h = 0; h < 2; h++) {
                f16x8 t;
                #pragma unroll
                for (int jj = 0; jj < 8; jj++)
                    t[jj] = (f16)((a < 2 ? ofA[a & 1] : ofB[a & 1])[h*8 + jj]);
                *(f16x8*)(base + a*32 + h*16) = t;
            }
        }
        *(float*)(base + 128) = ls;          // own q-tile's denominator partial
    }
    __syncthreads();
    if (w < 2) {
        unsigned char* base = lds_raw + (size_t)cp*9216 + (size_t)lane*144;
        #pragma unroll
        for (int a = 0; a < 4; a++) {
            #pragma unroll
            for (int h = 0; h < 2; h++) {
                f16x8 t = *(const f16x8*)(base + a*32 + h*16);
                #pragma unroll
                for (int jj = 0; jj < 8; jj++) {
                    float v = (float)t[jj];
                    if (a < 2) ofA[a & 1][h*8 + jj] += v;
                    else       ofB[a & 1][h*8 + jj] += v;
                }
            }
        }
        ls += *(const float*)(base + 128);
        // lead wave (0,cp) now has the full denominator for q-tile cp
        float* ls_inv = (float*)(lds_raw + 18432);
        if (lane < 32) ls_inv[cp*32 + n32] = 1.f / ls;
    }
    __syncthreads();

    // normalize + transpose into Tb[c][q] (waves 0,1 own 64 channels each)
    if (w < 2) {
        const float* ls_inv = (const float*)(lds_raw + 18432);
        float* Tb = (float*)(lds_raw + 18688);
        #pragma unroll
        for (int qts = 0; qts < 2; qts++) {
            #pragma unroll
            for (int j = 0; j < 4; j++) {
                f32x4v iv = *(const f32x4v*)&ls_inv[qts*32 + 8*j + 4*half];
                #pragma unroll
                for (int ctl = 0; ctl < 2; ctl++) {
                    const int c = (2*cp + ctl)*32 + n32;
                    f32x4v o;
                    #pragma unroll
                    for (int e = 0; e < 4; e++)
                        o[e] = (qts ? ofB[ctl] : ofA[ctl])[4*j + e] * iv[e];
                    *(f32x4v*)&Tb[(size_t)c*68 + qts*32 + 8*j + 4*half] = o;
                }
            }
        }
    }
    __syncthreads();
    {
        const float* Tb = (const float*)(lds_raw + 18688);
        #pragma unroll
        for (int it = 0; it < 8; it++) {
            int idx = it*256 + tid;
            int c = idx >> 4, qg = idx & 15;
            f32x4v v = *(const f32x4v*)&Tb[(size_t)c*68 + qg*4];
            // non-temporal: keep the 16 MB output stream out of L2
            __builtin_nontemporal_store(v,
                (f32x4v*)&out[((size_t)b*CC + c)*NN + q0 + qg*4]);
        }
    }
}

extern "C" void kernel_launch(void* const* d_in, const int* in_sizes, int n_in,
                              void* d_out, int out_size, void* d_ws, size_t ws_size,
                              hipStream_t stream) {
    const float* x  = (const float*)d_in[0];
    const float* Wq = (const float*)d_in[1];
    const float* bq = (const float*)d_in[2];
    const float* Wk = (const float*)d_in[3];
    const float* bk = (const float*)d_in[4];
    const float* Wv = (const float*)d_in[5];
    const float* bv = (const float*)d_in[6];
    float* out = (float*)d_out;

    // workspace: Qt,Kt f16 [B][N][16] (1MB each), Vf f16 sigma-fragments (8MB)
    f16* Qw = (f16*)d_ws;
    f16* Kw = Qw + (size_t)BB*NN*16;
    f16* Vw = Kw + (size_t)BB*NN*16;
    unsigned char* tail = (unsigned char*)d_out + (size_t)out_size*4 - WF_BYTES;
    f16*   Wf    = (f16*)tail;
    float* biasS = (float*)(tail + 49152);

    hipLaunchKernelGGL(prep_kernel, dim3(10), dim3(256), 0, stream,
                       Wq, bq, Wk, bk, Wv, bv, Wf, biasS);
    hipLaunchKernelGGL(proj_kernel, dim3(256), dim3(256), 0, stream,
                       x, Wf, biasS, Qw, Kw, Vw);
    hipLaunchKernelGGL(attn_kernel, dim3(512), dim3(256), 0, stream,
                       Qw, Kw, Vw, out);
}